// Round 10
// baseline (92.720 us; speedup 1.0000x reference)
//
#include <hip/hip_runtime.h>
#include <hip/hip_bf16.h>

typedef __bf16 bf16_t;
typedef bf16_t bf16x8 __attribute__((ext_vector_type(8)));
typedef bf16_t bf16x4 __attribute__((ext_vector_type(4)));
typedef float f32x4 __attribute__((ext_vector_type(4)));

#define MFMA16(a, b, c) __builtin_amdgcn_mfma_f32_16x16x32_bf16((a), (b), (c), 0, 0, 0)

// B=8, T=2048, E=1024, H=128
#define TT 2048
#define EE 1024
#define HH 128
#define UPB 288   // partial slots per batch: sum over 64 qtiles of (qt>>3)+1

// Fragment-major layouts (consumer = attn MFMA fragments, 1 coalesced load each):
//  Qf/Kf: chunk(grt, kk) = 64 lanes x 16B; lane g*16+c elem e = M[grt*16+c][kk*32+g*8+e]
//  Vf:    chunk(b, vc, hb) = 64 lanes x 16B; lane g*16+c elem j = V[b][vc*32+g*8+j][hb*16+c]

// ---------------- prep: Wt[w][n][k] = W[w][k][n], f32 -> bf16 ----------------
__global__ __launch_bounds__(256) void prep_w_kernel(
    const float* __restrict__ Wq, const float* __restrict__ Wk,
    const float* __restrict__ Wv, bf16_t* __restrict__ Wt)
{
    int idx = blockIdx.x * 256 + threadIdx.x;   // 0 .. 3*131072-1
    int w = idx >> 17;
    int r = idx & 131071;                        // n*1024 + k
    int n = r >> 10, k = r & 1023;
    const float* W = (w == 0) ? Wq : (w == 1) ? Wk : Wv;
    Wt[idx] = (bf16_t)W[k * HH + n];
}

// ---------------- fused QKV GEMM: [16384 x 1024] x [1024 x 384] ----------------
// 512 blocks (2/CU) x 256 thr (4 waves); BM=32, BN=384 (wave 32x96), BK=32.
// Depth-3 register pipeline on x (1 float4/thread/tile): load(t+3) at phase
// top, LDS-write(t+1) at phase bottom => ~2.7 phases in flight. W-frags
// double-reg-buffered (L2-resident). Tiny LDS dbuf, one barrier per phase.
// Fully-unrolled K-loop keeps all pipeline indices compile-time (reg-resident).
__global__ __launch_bounds__(256) void qkv_kernel(
    const float* __restrict__ x, const bf16_t* __restrict__ Wt,
    bf16_t* __restrict__ Qf, bf16_t* __restrict__ Kf, bf16_t* __restrict__ Vf)
{
    __shared__ __attribute__((aligned(16))) bf16_t As[2][32][40];
    const int row0 = blockIdx.x * 32;
    const int tid  = threadIdx.x;
    const int lane = tid & 63;
    const int wn   = tid >> 6;                    // 4 waves: 96-col slices
    const int g = lane >> 4, c = lane & 15;
    const int srow = tid >> 3;                    // 0..31
    const int scol = (tid & 7) * 4;               // f32 col within tile

    const float* xp = x + (size_t)(row0 + srow) * EE + scol;

    const bf16_t* wrow[6];
    for (int nt = 0; nt < 6; ++nt) {
        int cb = wn * 96 + nt * 16;
        wrow[nt] = Wt + ((size_t)(cb >> 7) * HH + (cb & 127) + c) * EE + g * 8;
    }

    f32x4 acc[2][6];
    for (int i = 0; i < 2; ++i)
        for (int j = 0; j < 6; ++j) acc[i][j] = (f32x4)0.0f;

    f32x4 pf[3];
    bf16x8 w[2][6];

#define WRITEPF(S, BUF) do {                                                  \
    union { bf16_t h[4]; unsigned long long u; } pk_;                         \
    pk_.h[0] = (bf16_t)pf[S][0]; pk_.h[1] = (bf16_t)pf[S][1];                 \
    pk_.h[2] = (bf16_t)pf[S][2]; pk_.h[3] = (bf16_t)pf[S][3];                 \
    *reinterpret_cast<unsigned long long*>(&As[BUF][srow][scol]) = pk_.u;     \
} while (0)

    pf[0] = *(const f32x4*)(xp);
    pf[1] = *(const f32x4*)(xp + 32);
    pf[2] = *(const f32x4*)(xp + 64);
    for (int nt = 0; nt < 6; ++nt) w[0][nt] = *(const bf16x8*)(wrow[nt]);
    for (int nt = 0; nt < 6; ++nt) w[1][nt] = *(const bf16x8*)(wrow[nt] + 32);
    WRITEPF(0, 0);
    __syncthreads();

#pragma unroll
    for (int t = 0; t < 32; ++t) {
        if (t + 3 < 32) pf[(t + 3) % 3] = *(const f32x4*)(xp + (size_t)(t + 3) * 32);
        for (int mt = 0; mt < 2; ++mt) {
            bf16x8 af = *(const bf16x8*)&As[t & 1][mt * 16 + c][g * 8];
            for (int nt = 0; nt < 6; ++nt)
                acc[mt][nt] = MFMA16(af, w[t & 1][nt], acc[mt][nt]);
        }
        if (t + 2 < 32)
            for (int nt = 0; nt < 6; ++nt)
                w[t & 1][nt] = *(const bf16x8*)(wrow[nt] + (size_t)(t + 2) * 32);
        if (t + 1 < 32) WRITEPF((t + 1) % 3, (t + 1) & 1);
        __syncthreads();
    }
#undef WRITEPF

    const float sc = 0.08838834764831845f * 1.4426950408889634f; // 1/sqrt(128)*log2e
    for (int mt = 0; mt < 2; ++mt)
        for (int nt = 0; nt < 6; ++nt) {
            int cb = wn * 96 + nt * 16;
            int w_  = cb >> 7;
            int hl = (cb & 127) + c;             // col within Q/K/V
            int t0 = row0 + mt * 16 + g * 4;     // global row
            if (w_ == 2) {
                // V fragment-major: pack 4 consecutive rows (same chunk, j0..j0+3)
                int b  = t0 >> 11;
                int tt = t0 & (TT - 1);
                int vc = tt >> 5, gg = (tt & 31) >> 3, j0 = tt & 7;
                int hb = hl >> 4, cc = hl & 15;
                union { bf16_t h4[4]; unsigned long long u; } pk;
                for (int i = 0; i < 4; ++i) pk.h4[i] = (bf16_t)acc[mt][nt][i];
                *reinterpret_cast<unsigned long long*>(
                    Vf + ((size_t)((b * 64 + vc) * 8 + hb)) * 512 +
                    (gg * 16 + cc) * 8 + j0) = pk.u;
            } else {
                bf16_t* dst = (w_ == 0) ? Qf : Kf;
                float s = (w_ == 0) ? sc : 1.0f;
                int kk = hl >> 5, gg = (hl & 31) >> 3, e = hl & 7;
                int grt = t0 >> 4;
                for (int i = 0; i < 4; ++i) {
                    int cr = (t0 + i) & 15;
                    dst[((size_t)(grt * 4 + kk)) * 512 + (gg * 16 + cr) * 8 + e] =
                        (bf16_t)(acc[mt][nt][i] * s);
                }
            }
        }
}

// ---------------- flash attention, split-KV partials, fragment-major I/O ----------------
// unit = (b, 32-row qtile, kvchunk256); one wave per unit, 4 units/block.
// blockIdx&7 = b -> XCD-pinned batch. Every Q/K/V load = 1 coalesced 1KB instr.
__global__ __launch_bounds__(256) void attn_kernel(
    const bf16_t* __restrict__ Qf, const bf16_t* __restrict__ Kf,
    const bf16_t* __restrict__ Vf, bf16_t* __restrict__ Pacc,
    float* __restrict__ Pml)
{
    __shared__ __attribute__((aligned(16))) bf16_t Pl[4][32][40];
    const int tid = threadIdx.x, lane = tid & 63, wid = tid >> 6;
    const int g = lane >> 4, c = lane & 15;
    bf16_t (*P)[40] = Pl[wid];

    const int bx = blockIdx.x;
    const int b  = bx & 7;                       // XCD-pinned batch
    const int u  = 287 - ((bx >> 3) * 4 + wid);  // long-units-first
    int k = 0;
    while (4 * (k + 1) * (k + 2) <= u) ++k;      // tier k = qt>>3, 0..7
    const int r  = u - 4 * k * (k + 1);
    const int qt = 8 * k + r / (k + 1);
    const int ch = r - (r / (k + 1)) * (k + 1);
    const int q0 = qt * 32;
    const int kv_lo = ch * 256;
    int kv_hi = kv_lo + 256; if (kv_hi > q0 + 32) kv_hi = q0 + 32;
    const int sid = b * UPB + 4 * k * (k + 1) + (qt & 7) * (k + 1) + ch;

    bf16x8 qA[4], qB[4];
    for (int kk = 0; kk < 4; ++kk) {
        qA[kk] = *(const bf16x8*)(Qf +
            ((size_t)((b * 128 + (q0 >> 4)) * 4 + kk)) * 512 + lane * 8);
        qB[kk] = *(const bf16x8*)(Qf +
            ((size_t)((b * 128 + (q0 >> 4) + 1) * 4 + kk)) * 512 + lane * 8);
    }

    f32x4 accA[8], accB[8];
    for (int hb = 0; hb < 8; ++hb) { accA[hb] = (f32x4)0.0f; accB[hb] = (f32x4)0.0f; }
    float lsA[4] = {0, 0, 0, 0}, lsB[4] = {0, 0, 0, 0};

    for (int kv0 = kv_lo; kv0 < kv_hi; kv0 += 32) {
        const int kt = b * 128 + (kv0 >> 4);
        bf16x8 k0f[4], k1f[4], vf[8];
        for (int kk = 0; kk < 4; ++kk) {
            k0f[kk] = *(const bf16x8*)(Kf + ((size_t)(kt * 4 + kk)) * 512 + lane * 8);
            k1f[kk] = *(const bf16x8*)(Kf + ((size_t)((kt + 1) * 4 + kk)) * 512 + lane * 8);
        }
        const int vcb = (b * 64 + (kv0 >> 5)) * 8;
        for (int hb = 0; hb < 8; ++hb)
            vf[hb] = *(const bf16x8*)(Vf + ((size_t)(vcb + hb)) * 512 + lane * 8);

        f32x4 sA0 = (f32x4)0.0f, sA1 = (f32x4)0.0f;
        f32x4 sB0 = (f32x4)0.0f, sB1 = (f32x4)0.0f;
        for (int kk = 0; kk < 4; ++kk) {
            sA0 = MFMA16(qA[kk], k0f[kk], sA0);
            sA1 = MFMA16(qA[kk], k1f[kk], sA1);
            sB0 = MFMA16(qB[kk], k0f[kk], sB0);
            sB1 = MFMA16(qB[kk], k1f[kk], sB1);
        }
        if (kv0 + 32 > q0) {                     // causal mask, subtile A
            for (int i = 0; i < 4; ++i) {
                int row = q0 + g * 4 + i;
                if (kv0 + c > row)      sA0[i] = -1e30f;
                if (kv0 + 16 + c > row) sA1[i] = -1e30f;
            }
        }
        if (kv0 + 32 > q0 + 16) {                // causal mask, subtile B
            for (int i = 0; i < 4; ++i) {
                int row = q0 + 16 + g * 4 + i;
                if (kv0 + c > row)      sB0[i] = -1e30f;
                if (kv0 + 16 + c > row) sB1[i] = -1e30f;
            }
        }
        float pA0[4], pA1[4], pB0[4], pB1[4];
        for (int i = 0; i < 4; ++i) {            // p = 2^s (log2e folded into Q)
            pA0[i] = exp2f(sA0[i]); pA1[i] = exp2f(sA1[i]);
            pB0[i] = exp2f(sB0[i]); pB1[i] = exp2f(sB1[i]);
            lsA[i] += pA0[i] + pA1[i];
            lsB[i] += pB0[i] + pB1[i];
        }
        for (int i = 0; i < 4; ++i) {
            P[g * 4 + i][c]           = (bf16_t)pA0[i];
            P[g * 4 + i][c + 16]      = (bf16_t)pA1[i];
            P[16 + g * 4 + i][c]      = (bf16_t)pB0[i];
            P[16 + g * 4 + i][c + 16] = (bf16_t)pB1[i];
        }
        __builtin_amdgcn_wave_barrier();
        asm volatile("s_waitcnt lgkmcnt(0)" ::: "memory");
        __builtin_amdgcn_sched_barrier(0);
        bf16x8 paA = *(const bf16x8*)&P[c][g * 8];
        bf16x8 paB = *(const bf16x8*)&P[16 + c][g * 8];
        __builtin_amdgcn_s_setprio(1);
        for (int hb = 0; hb < 8; ++hb) {
            accA[hb] = MFMA16(paA, vf[hb], accA[hb]);
            accB[hb] = MFMA16(paB, vf[hb], accB[hb]);
        }
        __builtin_amdgcn_s_setprio(0);
        __builtin_amdgcn_wave_barrier();
    }

    for (int off = 1; off < 16; off <<= 1)
        for (int i = 0; i < 4; ++i) {
            lsA[i] += __shfl_xor(lsA[i], off, 64);
            lsB[i] += __shfl_xor(lsB[i], off, 64);
        }
    if (c == 0)
        for (int i = 0; i < 4; ++i) {
            Pml[(size_t)sid * 32 + g * 4 + i]      = lsA[i];
            Pml[(size_t)sid * 32 + 16 + g * 4 + i] = lsB[i];
        }

    // Pacc transposed: po[col=128][row=32]; packed 8B stores
    bf16_t* po = Pacc + (size_t)sid * (32 * 128);
    for (int hb = 0; hb < 8; ++hb) {
        union { bf16_t h4[4]; unsigned long long u; } pa, pb;
        for (int i = 0; i < 4; ++i) {
            pa.h4[i] = (bf16_t)accA[hb][i];
            pb.h4[i] = (bf16_t)accB[hb][i];
        }
        bf16_t* cp = po + (hb * 16 + c) * 32;
        *reinterpret_cast<unsigned long long*>(cp + g * 4)      = pa.u;
        *reinterpret_cast<unsigned long long*>(cp + 16 + g * 4) = pb.u;
    }
}

// ---------------- combine partials (plain sums; Pacc is [col][row]) ----------------
__global__ __launch_bounds__(128) void combine_kernel(
    const bf16_t* __restrict__ Pacc, const float* __restrict__ Pml,
    float* __restrict__ out)
{
    __shared__ float invL[32];
    const int qt = blockIdx.x;                   // 0..63
    const int b  = blockIdx.y;
    const int k  = qt >> 3;
    const int base  = b * UPB + 4 * k * (k + 1) + (qt & 7) * (k + 1);
    const int count = k + 1;
    const int tid = threadIdx.x;                 // = col 0..127

    if (tid < 32) {
        float L = 0.0f;
        for (int cu = 0; cu < count; ++cu)
            L += Pml[(size_t)(base + cu) * 32 + tid];
        invL[tid] = 1.0f / L;
    }
    __syncthreads();

    float s[32];
    for (int r = 0; r < 32; ++r) s[r] = 0.0f;
    for (int cu = 0; cu < count; ++cu) {
        const bf16_t* cp = Pacc + (size_t)(base + cu) * 4096 + tid * 32;
        for (int r8 = 0; r8 < 4; ++r8) {
            bf16x8 v = *(const bf16x8*)(cp + r8 * 8);
            for (int j = 0; j < 8; ++j) s[r8 * 8 + j] += (float)v[j];
        }
    }
    const int q0 = qt * 32;
    for (int r = 0; r < 32; ++r)
        out[((size_t)b * TT + q0 + r) * HH + tid] = s[r] * invL[r];
}

extern "C" void kernel_launch(void* const* d_in, const int* in_sizes, int n_in,
                              void* d_out, int out_size, void* d_ws, size_t ws_size,
                              hipStream_t stream)
{
    const float* x  = (const float*)d_in[0];
    const float* Wq = (const float*)d_in[1];
    const float* Wk = (const float*)d_in[2];
    const float* Wv = (const float*)d_in[3];

    char* ws = (char*)d_ws;
    bf16_t* Wt   = (bf16_t*)ws;                       // 768 KB
    bf16_t* Qf   = (bf16_t*)(ws + (1u  << 20));       // 4 MB fragment-major
    bf16_t* Kf   = (bf16_t*)(ws + (5u  << 20));       // 4 MB fragment-major
    bf16_t* Vf   = (bf16_t*)(ws + (9u  << 20));       // 4 MB fragment-major
    bf16_t* Pacc = (bf16_t*)(ws + (13u << 20));       // 2304*8192 B = 18.9 MB
    float*  Pml  = (float*) (ws + (32u << 20));       // 2304*128 B

    prep_w_kernel<<<1536, 256, 0, stream>>>(Wq, Wk, Wv, Wt);
    qkv_kernel<<<512, 256, 0, stream>>>(x, Wt, Qf, Kf, Vf);
    attn_kernel<<<576, 256, 0, stream>>>(Qf, Kf, Vf, Pacc, Pml);
    combine_kernel<<<dim3(64, 8), 128, 0, stream>>>(Pacc, Pml, (float*)d_out);
}

// Round 11
// 70.991 us; speedup vs baseline: 1.3061x; 1.3061x over previous
//
#include <hip/hip_runtime.h>
#include <hip/hip_bf16.h>

typedef __bf16 bf16_t;
typedef bf16_t bf16x8 __attribute__((ext_vector_type(8)));
typedef bf16_t bf16x4 __attribute__((ext_vector_type(4)));
typedef float f32x4 __attribute__((ext_vector_type(4)));

#define MFMA16(a, b, c) __builtin_amdgcn_mfma_f32_16x16x32_bf16((a), (b), (c), 0, 0, 0)

// B=8, T=2048, E=1024, H=128
#define TT 2048
#define EE 1024
#define HH 128
#define UPB 288   // partial slots per batch: sum over 64 qtiles of (qt>>3)+1

// Fragment-major layouts (every consumer load = one coalesced 64x16B instr):
//  Wf: chunk(ct,kt): lane(g,c) elem e = W_{ct>>3}[k=kt*32+g*8+e][n=(ct&7)*16+c]
//  Qf/Kf: chunk(grt,kk): lane(g,c) elem e = M[grt*16+c][kk*32+g*8+e]
//  Vf: chunk(b,vc,hb): lane(g,c) elem j = V[b][vc*32+g*8+j][hb*16+c]

// ---------------- prep: Wf fragment-major, f32 -> bf16 ----------------
__global__ __launch_bounds__(256) void prep_w_kernel(
    const float* __restrict__ Wq, const float* __restrict__ Wk,
    const float* __restrict__ Wv, bf16_t* __restrict__ Wf)
{
    int idx = blockIdx.x * 256 + threadIdx.x;   // 0 .. 393215
    int e  = idx & 7;
    int c  = (idx >> 3) & 15;
    int g  = (idx >> 7) & 3;
    int kt = (idx >> 9) & 31;
    int ct = idx >> 14;                          // 0..23
    int w  = ct >> 3;
    const float* W = (w == 0) ? Wq : (w == 1) ? Wk : Wv;
    int k = kt * 32 + g * 8 + e;
    int n = (ct & 7) * 16 + c;
    Wf[idx] = (bf16_t)W[k * HH + n];
}

// ---------------- fused QKV GEMM: [16384 x 1024] x [1024 x 384] ----------------
// 256 blocks (1/CU) x 256 thr (4 waves); tile 64 rows x 384 cols; wave 64x96.
// x reg-pipelined 2 tiles ahead (load t+2 at top, LDS-write t+1 at bottom);
// W-frags fragment-major (1 coalesced dwordx4 each), prefetched 2 ahead.
// Epilogue writes fragment-major Qf/Kf/Vf.
__global__ __launch_bounds__(256) void qkv_kernel(
    const float* __restrict__ x, const bf16_t* __restrict__ Wf,
    bf16_t* __restrict__ Qf, bf16_t* __restrict__ Kf, bf16_t* __restrict__ Vf)
{
    __shared__ __attribute__((aligned(16))) bf16_t As[2][64][40];
    const int row0 = blockIdx.x * 64;
    const int tid  = threadIdx.x;
    const int lane = tid & 63;
    const int wn   = tid >> 6;                    // 4 waves: 96-col slices
    const int g = lane >> 4, c = lane & 15;

    const int row_a = tid >> 3;                   // 0..31
    const int row_b = 32 + row_a;
    const int col4  = (tid & 7) * 4;              // element col within 32-tile
    const float* xA = x + (size_t)(row0 + row_a) * EE + col4;
    const float* xB = x + (size_t)(row0 + row_b) * EE + col4;

    // W fragment base: wave wn covers ct = wn*6 .. wn*6+5
    const bf16_t* wfbase = Wf + (size_t)wn * 6 * 32 * 512 + lane * 8;
    // frag(nt, t) at wfbase + (nt*32 + t)*512

    f32x4 acc[4][6];
    for (int i = 0; i < 4; ++i)
        for (int j = 0; j < 6; ++j) acc[i][j] = (f32x4)0.0f;

    f32x4 fA[2], fB[2];
    bf16x8 w[2][6];

#define PHASE(CUR, OTH, T) do {                                               \
    if ((T) + 2 < 32) {                                                       \
        fA[CUR] = *(const f32x4*)(xA + (size_t)((T) + 2) * 32);               \
        fB[CUR] = *(const f32x4*)(xB + (size_t)((T) + 2) * 32);               \
    }                                                                         \
    for (int mt = 0; mt < 4; ++mt) {                                          \
        bf16x8 af = *(const bf16x8*)&As[CUR][mt * 16 + c][g * 8];             \
        for (int nt = 0; nt < 6; ++nt)                                        \
            acc[mt][nt] = MFMA16(af, w[CUR][nt], acc[mt][nt]);                \
    }                                                                         \
    if ((T) + 2 < 32)                                                         \
        for (int nt = 0; nt < 6; ++nt)                                        \
            w[CUR][nt] = *(const bf16x8*)(wfbase +                            \
                ((size_t)nt * 32 + (T) + 2) * 512);                           \
    if ((T) + 1 < 32) {                                                       \
        union { bf16_t h[4]; unsigned long long u; } p0_, p1_;                \
        p0_.h[0] = (bf16_t)fA[OTH][0]; p0_.h[1] = (bf16_t)fA[OTH][1];         \
        p0_.h[2] = (bf16_t)fA[OTH][2]; p0_.h[3] = (bf16_t)fA[OTH][3];         \
        p1_.h[0] = (bf16_t)fB[OTH][0]; p1_.h[1] = (bf16_t)fB[OTH][1];         \
        p1_.h[2] = (bf16_t)fB[OTH][2]; p1_.h[3] = (bf16_t)fB[OTH][3];         \
        *reinterpret_cast<unsigned long long*>(&As[OTH][row_a][col4]) = p0_.u;\
        *reinterpret_cast<unsigned long long*>(&As[OTH][row_b][col4]) = p1_.u;\
    }                                                                         \
    __syncthreads();                                                          \
} while (0)

    // prologue: tiles 0,1 into reg sets 0,1; W frags 0,1; write tile0 to LDS0
    fA[0] = *(const f32x4*)(xA);
    fB[0] = *(const f32x4*)(xB);
    fA[1] = *(const f32x4*)(xA + 32);
    fB[1] = *(const f32x4*)(xB + 32);
    for (int nt = 0; nt < 6; ++nt) {
        w[0][nt] = *(const bf16x8*)(wfbase + ((size_t)nt * 32) * 512);
        w[1][nt] = *(const bf16x8*)(wfbase + ((size_t)nt * 32 + 1) * 512);
    }
    {
        union { bf16_t h[4]; unsigned long long u; } p0_, p1_;
        p0_.h[0] = (bf16_t)fA[0][0]; p0_.h[1] = (bf16_t)fA[0][1];
        p0_.h[2] = (bf16_t)fA[0][2]; p0_.h[3] = (bf16_t)fA[0][3];
        p1_.h[0] = (bf16_t)fB[0][0]; p1_.h[1] = (bf16_t)fB[0][1];
        p1_.h[2] = (bf16_t)fB[0][2]; p1_.h[3] = (bf16_t)fB[0][3];
        *reinterpret_cast<unsigned long long*>(&As[0][row_a][col4]) = p0_.u;
        *reinterpret_cast<unsigned long long*>(&As[0][row_b][col4]) = p1_.u;
    }
    __syncthreads();

    for (int tt = 0; tt < 32; tt += 2) {
        PHASE(0, 1, tt);
        PHASE(1, 0, tt + 1);
    }
#undef PHASE

    const float sc = 0.08838834764831845f * 1.4426950408889634f; // 1/sqrt(128)*log2e
    for (int mt = 0; mt < 4; ++mt)
        for (int nt = 0; nt < 6; ++nt) {
            int cb = wn * 96 + nt * 16;
            int w_ = cb >> 7;
            int hl = (cb & 127) + c;             // col within Q/K/V
            int t0 = row0 + mt * 16 + g * 4;     // global row
            if (w_ == 2) {
                int b  = t0 >> 11;
                int ttr = t0 & (TT - 1);
                int vc = ttr >> 5, gg = (ttr & 31) >> 3, j0 = ttr & 7;
                int hb = hl >> 4, cc = hl & 15;
                union { bf16_t h4[4]; unsigned long long u; } pk;
                for (int i = 0; i < 4; ++i) pk.h4[i] = (bf16_t)acc[mt][nt][i];
                *reinterpret_cast<unsigned long long*>(
                    Vf + ((size_t)((b * 64 + vc) * 8 + hb)) * 512 +
                    (gg * 16 + cc) * 8 + j0) = pk.u;
            } else {
                bf16_t* dst = (w_ == 0) ? Qf : Kf;
                float s = (w_ == 0) ? sc : 1.0f;
                int kk = hl >> 5, gg = (hl & 31) >> 3, e = hl & 7;
                int grt = t0 >> 4;
                for (int i = 0; i < 4; ++i) {
                    int cr = (t0 + i) & 15;
                    dst[((size_t)(grt * 4 + kk)) * 512 + (gg * 16 + cr) * 8 + e] =
                        (bf16_t)(acc[mt][nt][i] * s);
                }
            }
        }
}

// ---------------- flash attention, split-KV partials, fragment-major I/O ----------------
// unit = (b, 32-row qtile, kvchunk256); one wave per unit, 4 units/block.
// blockIdx&7 = b -> XCD-pinned batch. Every Q/K/V load = 1 coalesced 1KB instr.
__global__ __launch_bounds__(256) void attn_kernel(
    const bf16_t* __restrict__ Qf, const bf16_t* __restrict__ Kf,
    const bf16_t* __restrict__ Vf, bf16_t* __restrict__ Pacc,
    float* __restrict__ Pml)
{
    __shared__ __attribute__((aligned(16))) bf16_t Pl[4][32][40];
    const int tid = threadIdx.x, lane = tid & 63, wid = tid >> 6;
    const int g = lane >> 4, c = lane & 15;
    bf16_t (*P)[40] = Pl[wid];

    const int bx = blockIdx.x;
    const int b  = bx & 7;                       // XCD-pinned batch
    const int u  = 287 - ((bx >> 3) * 4 + wid);  // long-units-first
    int k = 0;
    while (4 * (k + 1) * (k + 2) <= u) ++k;      // tier k = qt>>3, 0..7
    const int r  = u - 4 * k * (k + 1);
    const int qt = 8 * k + r / (k + 1);
    const int ch = r - (r / (k + 1)) * (k + 1);
    const int q0 = qt * 32;
    const int kv_lo = ch * 256;
    int kv_hi = kv_lo + 256; if (kv_hi > q0 + 32) kv_hi = q0 + 32;
    const int sid = b * UPB + 4 * k * (k + 1) + (qt & 7) * (k + 1) + ch;

    bf16x8 qA[4], qB[4];
    for (int kk = 0; kk < 4; ++kk) {
        qA[kk] = *(const bf16x8*)(Qf +
            ((size_t)((b * 128 + (q0 >> 4)) * 4 + kk)) * 512 + lane * 8);
        qB[kk] = *(const bf16x8*)(Qf +
            ((size_t)((b * 128 + (q0 >> 4) + 1) * 4 + kk)) * 512 + lane * 8);
    }

    f32x4 accA[8], accB[8];
    for (int hb = 0; hb < 8; ++hb) { accA[hb] = (f32x4)0.0f; accB[hb] = (f32x4)0.0f; }
    float lsA[4] = {0, 0, 0, 0}, lsB[4] = {0, 0, 0, 0};

    for (int kv0 = kv_lo; kv0 < kv_hi; kv0 += 32) {
        const int kt = b * 128 + (kv0 >> 4);
        bf16x8 k0f[4], k1f[4], vf[8];
        for (int kk = 0; kk < 4; ++kk) {
            k0f[kk] = *(const bf16x8*)(Kf + ((size_t)(kt * 4 + kk)) * 512 + lane * 8);
            k1f[kk] = *(const bf16x8*)(Kf + ((size_t)((kt + 1) * 4 + kk)) * 512 + lane * 8);
        }
        const int vcb = (b * 64 + (kv0 >> 5)) * 8;
        for (int hb = 0; hb < 8; ++hb)
            vf[hb] = *(const bf16x8*)(Vf + ((size_t)(vcb + hb)) * 512 + lane * 8);

        f32x4 sA0 = (f32x4)0.0f, sA1 = (f32x4)0.0f;
        f32x4 sB0 = (f32x4)0.0f, sB1 = (f32x4)0.0f;
        for (int kk = 0; kk < 4; ++kk) {
            sA0 = MFMA16(qA[kk], k0f[kk], sA0);
            sA1 = MFMA16(qA[kk], k1f[kk], sA1);
            sB0 = MFMA16(qB[kk], k0f[kk], sB0);
            sB1 = MFMA16(qB[kk], k1f[kk], sB1);
        }
        if (kv0 + 32 > q0) {                     // causal mask, subtile A
            for (int i = 0; i < 4; ++i) {
                int row = q0 + g * 4 + i;
                if (kv0 + c > row)      sA0[i] = -1e30f;
                if (kv0 + 16 + c > row) sA1[i] = -1e30f;
            }
        }
        if (kv0 + 32 > q0 + 16) {                // causal mask, subtile B
            for (int i = 0; i < 4; ++i) {
                int row = q0 + 16 + g * 4 + i;
                if (kv0 + c > row)      sB0[i] = -1e30f;
                if (kv0 + 16 + c > row) sB1[i] = -1e30f;
            }
        }
        float pA0[4], pA1[4], pB0[4], pB1[4];
        for (int i = 0; i < 4; ++i) {            // p = 2^s (log2e folded into Q)
            pA0[i] = exp2f(sA0[i]); pA1[i] = exp2f(sA1[i]);
            pB0[i] = exp2f(sB0[i]); pB1[i] = exp2f(sB1[i]);
            lsA[i] += pA0[i] + pA1[i];
            lsB[i] += pB0[i] + pB1[i];
        }
        for (int i = 0; i < 4; ++i) {
            P[g * 4 + i][c]           = (bf16_t)pA0[i];
            P[g * 4 + i][c + 16]      = (bf16_t)pA1[i];
            P[16 + g * 4 + i][c]      = (bf16_t)pB0[i];
            P[16 + g * 4 + i][c + 16] = (bf16_t)pB1[i];
        }
        __builtin_amdgcn_wave_barrier();
        asm volatile("s_waitcnt lgkmcnt(0)" ::: "memory");
        __builtin_amdgcn_sched_barrier(0);
        bf16x8 paA = *(const bf16x8*)&P[c][g * 8];
        bf16x8 paB = *(const bf16x8*)&P[16 + c][g * 8];
        __builtin_amdgcn_s_setprio(1);
        for (int hb = 0; hb < 8; ++hb) {
            accA[hb] = MFMA16(paA, vf[hb], accA[hb]);
            accB[hb] = MFMA16(paB, vf[hb], accB[hb]);
        }
        __builtin_amdgcn_s_setprio(0);
        __builtin_amdgcn_wave_barrier();
    }

    for (int off = 1; off < 16; off <<= 1)
        for (int i = 0; i < 4; ++i) {
            lsA[i] += __shfl_xor(lsA[i], off, 64);
            lsB[i] += __shfl_xor(lsB[i], off, 64);
        }
    if (c == 0)
        for (int i = 0; i < 4; ++i) {
            Pml[(size_t)sid * 32 + g * 4 + i]      = lsA[i];
            Pml[(size_t)sid * 32 + 16 + g * 4 + i] = lsB[i];
        }

    // Pacc transposed: po[col=128][row=32]; packed 8B stores
    bf16_t* po = Pacc + (size_t)sid * (32 * 128);
    for (int hb = 0; hb < 8; ++hb) {
        union { bf16_t h4[4]; unsigned long long u; } pa, pb;
        for (int i = 0; i < 4; ++i) {
            pa.h4[i] = (bf16_t)accA[hb][i];
            pb.h4[i] = (bf16_t)accB[hb][i];
        }
        bf16_t* cp = po + (hb * 16 + c) * 32;
        *reinterpret_cast<unsigned long long*>(cp + g * 4)      = pa.u;
        *reinterpret_cast<unsigned long long*>(cp + 16 + g * 4) = pb.u;
    }
}

// ---------------- combine partials (plain sums; Pacc is [col][row]) ----------------
__global__ __launch_bounds__(128) void combine_kernel(
    const bf16_t* __restrict__ Pacc, const float* __restrict__ Pml,
    float* __restrict__ out)
{
    __shared__ float invL[32];
    const int qt = blockIdx.x;                   // 0..63
    const int b  = blockIdx.y;
    const int k  = qt >> 3;
    const int base  = b * UPB + 4 * k * (k + 1) + (qt & 7) * (k + 1);
    const int count = k + 1;
    const int tid = threadIdx.x;                 // = col 0..127

    if (tid < 32) {
        float L = 0.0f;
        for (int cu = 0; cu < count; ++cu)
            L += Pml[(size_t)(base + cu) * 32 + tid];
        invL[tid] = 1.0f / L;
    }
    __syncthreads();

    float s[32];
    for (int r = 0; r < 32; ++r) s[r] = 0.0f;
    for (int cu = 0; cu < count; ++cu) {
        const bf16_t* cp = Pacc + (size_t)(base + cu) * 4096 + tid * 32;
        for (int r8 = 0; r8 < 4; ++r8) {
            bf16x8 v = *(const bf16x8*)(cp + r8 * 8);
            for (int j = 0; j < 8; ++j) s[r8 * 8 + j] += (float)v[j];
        }
    }
    const int q0 = qt * 32;
    for (int r = 0; r < 32; ++r)
        out[((size_t)b * TT + q0 + r) * HH + tid] = s[r] * invL[r];
}

extern "C" void kernel_launch(void* const* d_in, const int* in_sizes, int n_in,
                              void* d_out, int out_size, void* d_ws, size_t ws_size,
                              hipStream_t stream)
{
    const float* x  = (const float*)d_in[0];
    const float* Wq = (const float*)d_in[1];
    const float* Wk = (const float*)d_in[2];
    const float* Wv = (const float*)d_in[3];

    char* ws = (char*)d_ws;
    bf16_t* Wf   = (bf16_t*)ws;                       // 768 KB fragment-major
    bf16_t* Qf   = (bf16_t*)(ws + (1u  << 20));       // 4 MB fragment-major
    bf16_t* Kf   = (bf16_t*)(ws + (5u  << 20));       // 4 MB fragment-major
    bf16_t* Vf   = (bf16_t*)(ws + (9u  << 20));       // 4 MB fragment-major
    bf16_t* Pacc = (bf16_t*)(ws + (13u << 20));       // 2304*8192 B = 18.9 MB
    float*  Pml  = (float*) (ws + (32u << 20));       // 2304*128 B

    prep_w_kernel<<<1536, 256, 0, stream>>>(Wq, Wk, Wv, Wf);
    qkv_kernel<<<256, 256, 0, stream>>>(x, Wf, Qf, Kf, Vf);
    attn_kernel<<<576, 256, 0, stream>>>(Qf, Kf, Vf, Pacc, Pml);
    combine_kernel<<<dim3(64, 8), 128, 0, stream>>>(Pacc, Pml, (float*)d_out);
}

// Round 12
// 68.356 us; speedup vs baseline: 1.3564x; 1.0385x over previous
//
#include <hip/hip_runtime.h>
#include <hip/hip_bf16.h>

typedef __bf16 bf16_t;
typedef bf16_t bf16x8 __attribute__((ext_vector_type(8)));
typedef bf16_t bf16x4 __attribute__((ext_vector_type(4)));
typedef float f32x4 __attribute__((ext_vector_type(4)));

#define MFMA16(a, b, c) __builtin_amdgcn_mfma_f32_16x16x32_bf16((a), (b), (c), 0, 0, 0)

// B=8, T=2048, E=1024, H=128
#define TT 2048
#define EE 1024
#define HH 128
#define UPB 288   // partial slots per batch: sum over 64 qtiles of (qt>>3)+1

// Fragment-major layouts (every consumer load = one coalesced 64x16B instr):
//  Wf: chunk(ct,kt): lane(g,c) elem e = W_{ct>>3}[k=kt*32+g*8+e][n=(ct&7)*16+c]
//  Qf/Kf: chunk(grt,kk): lane(g,c) elem e = M[grt*16+c][kk*32+g*8+e]
//  Vf: chunk(b,vc,hb): lane(g,c) elem j = V[b][vc*32+g*8+j][hb*16+c]

// ---------------- prep: Wf fragment-major, f32 -> bf16 ----------------
__global__ __launch_bounds__(256) void prep_w_kernel(
    const float* __restrict__ Wq, const float* __restrict__ Wk,
    const float* __restrict__ Wv, bf16_t* __restrict__ Wf)
{
    int idx = blockIdx.x * 256 + threadIdx.x;   // 0 .. 393215
    int e  = idx & 7;
    int c  = (idx >> 3) & 15;
    int g  = (idx >> 7) & 3;
    int kt = (idx >> 9) & 31;
    int ct = idx >> 14;                          // 0..23
    int w  = ct >> 3;
    const float* W = (w == 0) ? Wq : (w == 1) ? Wk : Wv;
    int k = kt * 32 + g * 8 + e;
    int n = (ct & 7) * 16 + c;
    Wf[idx] = (bf16_t)W[k * HH + n];
}

// ---------------- fused QKV GEMM: [16384 x 1024] x [1024 x 384] ----------------
// 512 blocks (2 independent blocks/CU -> 2 waves/SIMD) x 256 thr (4 waves);
// BM=32, BN=384 (wave 32x96), BK=64 -> 16 phases of 24 MFMA/wave.
// x reg-pipelined 2 phases ahead (load t+2 top, LDS-write t+1 bottom);
// W frags fragment-major, double-reg-buffered. Epilogue: fragment-major out.
__global__ __launch_bounds__(256) void qkv_kernel(
    const float* __restrict__ x, const bf16_t* __restrict__ Wf,
    bf16_t* __restrict__ Qf, bf16_t* __restrict__ Kf, bf16_t* __restrict__ Vf)
{
    __shared__ __attribute__((aligned(16))) bf16_t As[2][32][72];  // 144B rows
    const int row0 = blockIdx.x * 32;
    const int tid  = threadIdx.x;
    const int lane = tid & 63;
    const int wn   = tid >> 6;                    // 4 waves: 96-col slices
    const int g = lane >> 4, c = lane & 15;

    // staging: 32 rows x 64 f32 cols per phase = 512 float4 slots, 2/thread
    const int srow0 = tid >> 4;                   // slot0 row (0..15)
    const int srow1 = 16 + srow0;
    const int scg   = (tid & 15) * 4;             // f32 col within 64-tile
    const float* xp0 = x + (size_t)(row0 + srow0) * EE + scg;
    const float* xp1 = x + (size_t)(row0 + srow1) * EE + scg;

    // W fragment base: wave wn covers ct = wn*6 .. wn*6+5
    const bf16_t* wfbase = Wf + (size_t)wn * 6 * 32 * 512 + lane * 8;
    // frag(nt, kt) at wfbase + (nt*32 + kt)*512, kt = t*2 + kk

    f32x4 acc[2][6];
    for (int i = 0; i < 2; ++i)
        for (int j = 0; j < 6; ++j) acc[i][j] = (f32x4)0.0f;

    f32x4 f0[2], f1[2];                           // [pipeline set]
    bf16x8 w[2][12];                              // [set][kk*6+nt]

#define XLOAD(S, T) do {                                                      \
    f0[S] = *(const f32x4*)(xp0 + (size_t)(T) * 64);                          \
    f1[S] = *(const f32x4*)(xp1 + (size_t)(T) * 64);                          \
} while (0)
#define WLOAD(S, T) do {                                                      \
    for (int kk = 0; kk < 2; ++kk)                                            \
        for (int nt = 0; nt < 6; ++nt)                                        \
            w[S][kk * 6 + nt] = *(const bf16x8*)(wfbase +                     \
                ((size_t)nt * 32 + (T) * 2 + kk) * 512);                      \
} while (0)
#define XWRITE(S, BUF) do {                                                   \
    union { bf16_t h[4]; unsigned long long u; } p0_, p1_;                    \
    p0_.h[0] = (bf16_t)f0[S][0]; p0_.h[1] = (bf16_t)f0[S][1];                 \
    p0_.h[2] = (bf16_t)f0[S][2]; p0_.h[3] = (bf16_t)f0[S][3];                 \
    p1_.h[0] = (bf16_t)f1[S][0]; p1_.h[1] = (bf16_t)f1[S][1];                 \
    p1_.h[2] = (bf16_t)f1[S][2]; p1_.h[3] = (bf16_t)f1[S][3];                 \
    *reinterpret_cast<unsigned long long*>(&As[BUF][srow0][scg]) = p0_.u;     \
    *reinterpret_cast<unsigned long long*>(&As[BUF][srow1][scg]) = p1_.u;     \
} while (0)
#define PHASE(CUR, OTH, T) do {                                               \
    if ((T) + 2 < 16) XLOAD(CUR, (T) + 2);                                    \
    for (int kk = 0; kk < 2; ++kk)                                            \
        for (int mt = 0; mt < 2; ++mt) {                                      \
            bf16x8 af = *(const bf16x8*)&As[CUR][mt * 16 + c][kk * 32 + g * 8]; \
            for (int nt = 0; nt < 6; ++nt)                                    \
                acc[mt][nt] = MFMA16(af, w[CUR][kk * 6 + nt], acc[mt][nt]);   \
        }                                                                     \
    if ((T) + 2 < 16) WLOAD(CUR, (T) + 2);                                    \
    if ((T) + 1 < 16) XWRITE(OTH, OTH);                                       \
    __syncthreads();                                                          \
} while (0)

    // prologue: x tiles 0,1 into reg sets; W frags 0,1; write tile0 to LDS0
    XLOAD(0, 0);
    XLOAD(1, 1);
    WLOAD(0, 0);
    WLOAD(1, 1);
    XWRITE(0, 0);
    __syncthreads();

    for (int tt = 0; tt < 16; tt += 2) {
        PHASE(0, 1, tt);
        PHASE(1, 0, tt + 1);
    }
#undef PHASE
#undef XLOAD
#undef WLOAD
#undef XWRITE

    const float sc = 0.08838834764831845f * 1.4426950408889634f; // 1/sqrt(128)*log2e
    for (int mt = 0; mt < 2; ++mt)
        for (int nt = 0; nt < 6; ++nt) {
            int cb = wn * 96 + nt * 16;
            int w_ = cb >> 7;
            int hl = (cb & 127) + c;             // col within Q/K/V
            int t0 = row0 + mt * 16 + g * 4;     // global row
            if (w_ == 2) {
                int b  = t0 >> 11;
                int ttr = t0 & (TT - 1);
                int vc = ttr >> 5, gg = (ttr & 31) >> 3, j0 = ttr & 7;
                int hb = hl >> 4, cc = hl & 15;
                union { bf16_t h4[4]; unsigned long long u; } pk;
                for (int i = 0; i < 4; ++i) pk.h4[i] = (bf16_t)acc[mt][nt][i];
                *reinterpret_cast<unsigned long long*>(
                    Vf + ((size_t)((b * 64 + vc) * 8 + hb)) * 512 +
                    (gg * 16 + cc) * 8 + j0) = pk.u;
            } else {
                bf16_t* dst = (w_ == 0) ? Qf : Kf;
                float s = (w_ == 0) ? sc : 1.0f;
                int kk = hl >> 5, gg = (hl & 31) >> 3, e = hl & 7;
                int grt = t0 >> 4;
                for (int i = 0; i < 4; ++i) {
                    int cr = (t0 + i) & 15;
                    dst[((size_t)(grt * 4 + kk)) * 512 + (gg * 16 + cr) * 8 + e] =
                        (bf16_t)(acc[mt][nt][i] * s);
                }
            }
        }
}

// ---------------- flash attention, split-KV partials, fragment-major I/O ----------------
// unit = (b, 32-row qtile, kvchunk256); one wave per unit, 4 units/block.
// blockIdx&7 = b -> XCD-pinned batch. Every Q/K/V load = 1 coalesced 1KB instr.
__global__ __launch_bounds__(256) void attn_kernel(
    const bf16_t* __restrict__ Qf, const bf16_t* __restrict__ Kf,
    const bf16_t* __restrict__ Vf, bf16_t* __restrict__ Pacc,
    float* __restrict__ Pml)
{
    __shared__ __attribute__((aligned(16))) bf16_t Pl[4][32][40];
    const int tid = threadIdx.x, lane = tid & 63, wid = tid >> 6;
    const int g = lane >> 4, c = lane & 15;
    bf16_t (*P)[40] = Pl[wid];

    const int bx = blockIdx.x;
    const int b  = bx & 7;                       // XCD-pinned batch
    const int u  = 287 - ((bx >> 3) * 4 + wid);  // long-units-first
    int k = 0;
    while (4 * (k + 1) * (k + 2) <= u) ++k;      // tier k = qt>>3, 0..7
    const int r  = u - 4 * k * (k + 1);
    const int qt = 8 * k + r / (k + 1);
    const int ch = r - (r / (k + 1)) * (k + 1);
    const int q0 = qt * 32;
    const int kv_lo = ch * 256;
    int kv_hi = kv_lo + 256; if (kv_hi > q0 + 32) kv_hi = q0 + 32;
    const int sid = b * UPB + 4 * k * (k + 1) + (qt & 7) * (k + 1) + ch;

    bf16x8 qA[4], qB[4];
    for (int kk = 0; kk < 4; ++kk) {
        qA[kk] = *(const bf16x8*)(Qf +
            ((size_t)((b * 128 + (q0 >> 4)) * 4 + kk)) * 512 + lane * 8);
        qB[kk] = *(const bf16x8*)(Qf +
            ((size_t)((b * 128 + (q0 >> 4) + 1) * 4 + kk)) * 512 + lane * 8);
    }

    f32x4 accA[8], accB[8];
    for (int hb = 0; hb < 8; ++hb) { accA[hb] = (f32x4)0.0f; accB[hb] = (f32x4)0.0f; }
    float lsA[4] = {0, 0, 0, 0}, lsB[4] = {0, 0, 0, 0};

    for (int kv0 = kv_lo; kv0 < kv_hi; kv0 += 32) {
        const int kt = b * 128 + (kv0 >> 4);
        bf16x8 k0f[4], k1f[4], vf[8];
        for (int kk = 0; kk < 4; ++kk) {
            k0f[kk] = *(const bf16x8*)(Kf + ((size_t)(kt * 4 + kk)) * 512 + lane * 8);
            k1f[kk] = *(const bf16x8*)(Kf + ((size_t)((kt + 1) * 4 + kk)) * 512 + lane * 8);
        }
        const int vcb = (b * 64 + (kv0 >> 5)) * 8;
        for (int hb = 0; hb < 8; ++hb)
            vf[hb] = *(const bf16x8*)(Vf + ((size_t)(vcb + hb)) * 512 + lane * 8);

        f32x4 sA0 = (f32x4)0.0f, sA1 = (f32x4)0.0f;
        f32x4 sB0 = (f32x4)0.0f, sB1 = (f32x4)0.0f;
        for (int kk = 0; kk < 4; ++kk) {
            sA0 = MFMA16(qA[kk], k0f[kk], sA0);
            sA1 = MFMA16(qA[kk], k1f[kk], sA1);
            sB0 = MFMA16(qB[kk], k0f[kk], sB0);
            sB1 = MFMA16(qB[kk], k1f[kk], sB1);
        }
        if (kv0 + 32 > q0) {                     // causal mask, subtile A
            for (int i = 0; i < 4; ++i) {
                int row = q0 + g * 4 + i;
                if (kv0 + c > row)      sA0[i] = -1e30f;
                if (kv0 + 16 + c > row) sA1[i] = -1e30f;
            }
        }
        if (kv0 + 32 > q0 + 16) {                // causal mask, subtile B
            for (int i = 0; i < 4; ++i) {
                int row = q0 + 16 + g * 4 + i;
                if (kv0 + c > row)      sB0[i] = -1e30f;
                if (kv0 + 16 + c > row) sB1[i] = -1e30f;
            }
        }
        float pA0[4], pA1[4], pB0[4], pB1[4];
        for (int i = 0; i < 4; ++i) {            // p = 2^s (log2e folded into Q)
            pA0[i] = exp2f(sA0[i]); pA1[i] = exp2f(sA1[i]);
            pB0[i] = exp2f(sB0[i]); pB1[i] = exp2f(sB1[i]);
            lsA[i] += pA0[i] + pA1[i];
            lsB[i] += pB0[i] + pB1[i];
        }
        for (int i = 0; i < 4; ++i) {
            P[g * 4 + i][c]           = (bf16_t)pA0[i];
            P[g * 4 + i][c + 16]      = (bf16_t)pA1[i];
            P[16 + g * 4 + i][c]      = (bf16_t)pB0[i];
            P[16 + g * 4 + i][c + 16] = (bf16_t)pB1[i];
        }
        __builtin_amdgcn_wave_barrier();
        asm volatile("s_waitcnt lgkmcnt(0)" ::: "memory");
        __builtin_amdgcn_sched_barrier(0);
        bf16x8 paA = *(const bf16x8*)&P[c][g * 8];
        bf16x8 paB = *(const bf16x8*)&P[16 + c][g * 8];
        __builtin_amdgcn_s_setprio(1);
        for (int hb = 0; hb < 8; ++hb) {
            accA[hb] = MFMA16(paA, vf[hb], accA[hb]);
            accB[hb] = MFMA16(paB, vf[hb], accB[hb]);
        }
        __builtin_amdgcn_s_setprio(0);
        __builtin_amdgcn_wave_barrier();
    }

    for (int off = 1; off < 16; off <<= 1)
        for (int i = 0; i < 4; ++i) {
            lsA[i] += __shfl_xor(lsA[i], off, 64);
            lsB[i] += __shfl_xor(lsB[i], off, 64);
        }
    if (c == 0)
        for (int i = 0; i < 4; ++i) {
            Pml[(size_t)sid * 32 + g * 4 + i]      = lsA[i];
            Pml[(size_t)sid * 32 + 16 + g * 4 + i] = lsB[i];
        }

    // Pacc transposed: po[col=128][row=32]; packed 8B stores
    bf16_t* po = Pacc + (size_t)sid * (32 * 128);
    for (int hb = 0; hb < 8; ++hb) {
        union { bf16_t h4[4]; unsigned long long u; } pa, pb;
        for (int i = 0; i < 4; ++i) {
            pa.h4[i] = (bf16_t)accA[hb][i];
            pb.h4[i] = (bf16_t)accB[hb][i];
        }
        bf16_t* cp = po + (hb * 16 + c) * 32;
        *reinterpret_cast<unsigned long long*>(cp + g * 4)      = pa.u;
        *reinterpret_cast<unsigned long long*>(cp + 16 + g * 4) = pb.u;
    }
}

// ---------------- combine partials (plain sums; Pacc is [col][row]) ----------------
__global__ __launch_bounds__(128) void combine_kernel(
    const bf16_t* __restrict__ Pacc, const float* __restrict__ Pml,
    float* __restrict__ out)
{
    __shared__ float invL[32];
    const int qt = blockIdx.x;                   // 0..63
    const int b  = blockIdx.y;
    const int k  = qt >> 3;
    const int base  = b * UPB + 4 * k * (k + 1) + (qt & 7) * (k + 1);
    const int count = k + 1;
    const int tid = threadIdx.x;                 // = col 0..127

    if (tid < 32) {
        float L = 0.0f;
        for (int cu = 0; cu < count; ++cu)
            L += Pml[(size_t)(base + cu) * 32 + tid];
        invL[tid] = 1.0f / L;
    }
    __syncthreads();

    float s[32];
    for (int r = 0; r < 32; ++r) s[r] = 0.0f;
    for (int cu = 0; cu < count; ++cu) {
        const bf16_t* cp = Pacc + (size_t)(base + cu) * 4096 + tid * 32;
        for (int r8 = 0; r8 < 4; ++r8) {
            bf16x8 v = *(const bf16x8*)(cp + r8 * 8);
            for (int j = 0; j < 8; ++j) s[r8 * 8 + j] += (float)v[j];
        }
    }
    const int q0 = qt * 32;
    for (int r = 0; r < 32; ++r)
        out[((size_t)b * TT + q0 + r) * HH + tid] = s[r] * invL[r];
}

extern "C" void kernel_launch(void* const* d_in, const int* in_sizes, int n_in,
                              void* d_out, int out_size, void* d_ws, size_t ws_size,
                              hipStream_t stream)
{
    const float* x  = (const float*)d_in[0];
    const float* Wq = (const float*)d_in[1];
    const float* Wk = (const float*)d_in[2];
    const float* Wv = (const float*)d_in[3];

    char* ws = (char*)d_ws;
    bf16_t* Wf   = (bf16_t*)ws;                       // 768 KB fragment-major
    bf16_t* Qf   = (bf16_t*)(ws + (1u  << 20));       // 4 MB fragment-major
    bf16_t* Kf   = (bf16_t*)(ws + (5u  << 20));       // 4 MB fragment-major
    bf16_t* Vf   = (bf16_t*)(ws + (9u  << 20));       // 4 MB fragment-major
    bf16_t* Pacc = (bf16_t*)(ws + (13u << 20));       // 2304*8192 B = 18.9 MB
    float*  Pml  = (float*) (ws + (32u << 20));       // 2304*128 B

    prep_w_kernel<<<1536, 256, 0, stream>>>(Wq, Wk, Wv, Wf);
    qkv_kernel<<<512, 256, 0, stream>>>(x, Wf, Qf, Kf, Vf);
    attn_kernel<<<576, 256, 0, stream>>>(Qf, Kf, Vf, Pacc, Pml);
    combine_kernel<<<dim3(64, 8), 128, 0, stream>>>(Pacc, Pml, (float*)d_out);
}

// Round 13
// 68.317 us; speedup vs baseline: 1.3572x; 1.0006x over previous
//
#include <hip/hip_runtime.h>
#include <hip/hip_bf16.h>

typedef __bf16 bf16_t;
typedef bf16_t bf16x8 __attribute__((ext_vector_type(8)));
typedef bf16_t bf16x4 __attribute__((ext_vector_type(4)));
typedef float f32x4 __attribute__((ext_vector_type(4)));

#define MFMA16(a, b, c) __builtin_amdgcn_mfma_f32_16x16x32_bf16((a), (b), (c), 0, 0, 0)

// B=8, T=2048, E=1024, H=128
#define TT 2048
#define EE 1024
#define HH 128
#define UPB 288   // partial slots per batch: sum over 64 qtiles of (qt>>3)+1

// Fragment-major layouts (every consumer load = one coalesced 64x16B instr):
//  Wf: chunk(ct,kt): lane(g,c) elem e = W_{ct>>3}[k=kt*32+g*8+e][n=(ct&7)*16+c]
//  Qf/Kf: chunk(grt,kk): lane(g,c) elem e = M[grt*16+c][kk*32+g*8+e]
//  Vf: chunk(b,vc,hb): lane(g,c) elem j = V[b][vc*32+g*8+j][hb*16+c]

// ---------------- prep: Wf fragment-major, f32 -> bf16 ----------------
__global__ __launch_bounds__(256) void prep_w_kernel(
    const float* __restrict__ Wq, const float* __restrict__ Wk,
    const float* __restrict__ Wv, bf16_t* __restrict__ Wf)
{
    int idx = blockIdx.x * 256 + threadIdx.x;   // 0 .. 393215
    int e  = idx & 7;
    int c  = (idx >> 3) & 15;
    int g  = (idx >> 7) & 3;
    int kt = (idx >> 9) & 31;
    int ct = idx >> 14;                          // 0..23
    int w  = ct >> 3;
    const float* W = (w == 0) ? Wq : (w == 1) ? Wk : Wv;
    int k = kt * 32 + g * 8 + e;
    int n = (ct & 7) * 16 + c;
    Wf[idx] = (bf16_t)W[k * HH + n];
}

// ---------------- fused QKV GEMM: [16384 x 1024] x [1024 x 384] ----------------
// 512 blocks (2/CU) x 256 thr (4 waves); BM=32, BN=384 (wave 32x96), BK=64.
// KEY (T4): raw s_barrier + lgkmcnt(0) only -- prefetch global loads stay in
// flight across the barrier (no vmcnt(0) drain); consumption waits are the
// compiler's counted register-dependency waitcnts.
__global__ __launch_bounds__(256) void qkv_kernel(
    const float* __restrict__ x, const bf16_t* __restrict__ Wf,
    bf16_t* __restrict__ Qf, bf16_t* __restrict__ Kf, bf16_t* __restrict__ Vf)
{
    __shared__ __attribute__((aligned(16))) bf16_t As[2][32][72];  // 144B rows
    const int row0 = blockIdx.x * 32;
    const int tid  = threadIdx.x;
    const int lane = tid & 63;
    const int wn   = tid >> 6;                    // 4 waves: 96-col slices
    const int g = lane >> 4, c = lane & 15;

    // staging: 32 rows x 64 f32 cols per phase = 512 float4 slots, 2/thread
    const int srow0 = tid >> 4;                   // 0..15
    const int srow1 = 16 + srow0;
    const int scg   = (tid & 15) * 4;             // f32 col within 64-tile
    const float* xp0 = x + (size_t)(row0 + srow0) * EE + scg;
    const float* xp1 = x + (size_t)(row0 + srow1) * EE + scg;

    // W fragment base: wave wn covers ct = wn*6 .. wn*6+5
    const bf16_t* wfbase = Wf + (size_t)wn * 6 * 32 * 512 + lane * 8;

    f32x4 acc[2][6];
    for (int i = 0; i < 2; ++i)
        for (int j = 0; j < 6; ++j) acc[i][j] = (f32x4)0.0f;

    f32x4 f0[2], f1[2];                           // [pipeline set]
    bf16x8 w[2][12];                              // [set][kk*6+nt]

#define BAR() do {                                                            \
    asm volatile("s_waitcnt lgkmcnt(0)" ::: "memory");                        \
    __builtin_amdgcn_s_barrier();                                             \
    __builtin_amdgcn_sched_barrier(0);                                        \
} while (0)
#define XLOAD(S, T) do {                                                      \
    f0[S] = *(const f32x4*)(xp0 + (size_t)(T) * 64);                          \
    f1[S] = *(const f32x4*)(xp1 + (size_t)(T) * 64);                          \
} while (0)
#define WLOAD(S, T) do {                                                      \
    for (int kk = 0; kk < 2; ++kk)                                            \
        for (int nt = 0; nt < 6; ++nt)                                        \
            w[S][kk * 6 + nt] = *(const bf16x8*)(wfbase +                     \
                ((size_t)nt * 32 + (T) * 2 + kk) * 512);                      \
} while (0)
#define XWRITE(S, BUF) do {                                                   \
    union { bf16_t h[4]; unsigned long long u; } p0_, p1_;                    \
    p0_.h[0] = (bf16_t)f0[S][0]; p0_.h[1] = (bf16_t)f0[S][1];                 \
    p0_.h[2] = (bf16_t)f0[S][2]; p0_.h[3] = (bf16_t)f0[S][3];                 \
    p1_.h[0] = (bf16_t)f1[S][0]; p1_.h[1] = (bf16_t)f1[S][1];                 \
    p1_.h[2] = (bf16_t)f1[S][2]; p1_.h[3] = (bf16_t)f1[S][3];                 \
    *reinterpret_cast<unsigned long long*>(&As[BUF][srow0][scg]) = p0_.u;     \
    *reinterpret_cast<unsigned long long*>(&As[BUF][srow1][scg]) = p1_.u;     \
} while (0)
#define PHASE(CUR, OTH, T) do {                                               \
    if ((T) + 2 < 16) XLOAD(CUR, (T) + 2);                                    \
    for (int kk = 0; kk < 2; ++kk)                                            \
        for (int mt = 0; mt < 2; ++mt) {                                      \
            bf16x8 af = *(const bf16x8*)&As[CUR][mt * 16 + c][kk * 32 + g * 8]; \
            for (int nt = 0; nt < 6; ++nt)                                    \
                acc[mt][nt] = MFMA16(af, w[CUR][kk * 6 + nt], acc[mt][nt]);   \
        }                                                                     \
    if ((T) + 2 < 16) WLOAD(CUR, (T) + 2);                                    \
    if ((T) + 1 < 16) XWRITE(OTH, OTH);                                       \
    BAR();                                                                    \
} while (0)

    // prologue: x tiles 0,1 into reg sets; W frags 0,1; write tile0 to LDS0
    XLOAD(0, 0);
    XLOAD(1, 1);
    WLOAD(0, 0);
    WLOAD(1, 1);
    XWRITE(0, 0);
    BAR();

    for (int tt = 0; tt < 16; tt += 2) {
        PHASE(0, 1, tt);
        PHASE(1, 0, tt + 1);
    }
#undef PHASE
#undef XLOAD
#undef WLOAD
#undef XWRITE
#undef BAR

    const float sc = 0.08838834764831845f * 1.4426950408889634f; // 1/sqrt(128)*log2e
    for (int mt = 0; mt < 2; ++mt)
        for (int nt = 0; nt < 6; ++nt) {
            int cb = wn * 96 + nt * 16;
            int w_ = cb >> 7;
            int hl = (cb & 127) + c;             // col within Q/K/V
            int t0 = row0 + mt * 16 + g * 4;     // global row
            if (w_ == 2) {
                int b  = t0 >> 11;
                int ttr = t0 & (TT - 1);
                int vc = ttr >> 5, gg = (ttr & 31) >> 3, j0 = ttr & 7;
                int hb = hl >> 4, cc = hl & 15;
                union { bf16_t h4[4]; unsigned long long u; } pk;
                for (int i = 0; i < 4; ++i) pk.h4[i] = (bf16_t)acc[mt][nt][i];
                *reinterpret_cast<unsigned long long*>(
                    Vf + ((size_t)((b * 64 + vc) * 8 + hb)) * 512 +
                    (gg * 16 + cc) * 8 + j0) = pk.u;
            } else {
                bf16_t* dst = (w_ == 0) ? Qf : Kf;
                float s = (w_ == 0) ? sc : 1.0f;
                int kk = hl >> 5, gg = (hl & 31) >> 3, e = hl & 7;
                int grt = t0 >> 4;
                for (int i = 0; i < 4; ++i) {
                    int cr = (t0 + i) & 15;
                    dst[((size_t)(grt * 4 + kk)) * 512 + (gg * 16 + cr) * 8 + e] =
                        (bf16_t)(acc[mt][nt][i] * s);
                }
            }
        }
}

// ---------------- flash attention, split-KV partials, fragment-major I/O ----------------
// unit = (b, 32-row qtile, kvchunk256); one wave per unit, 4 units/block.
// blockIdx&7 = b -> XCD-pinned batch. Every Q/K/V load = 1 coalesced 1KB instr.
__global__ __launch_bounds__(256) void attn_kernel(
    const bf16_t* __restrict__ Qf, const bf16_t* __restrict__ Kf,
    const bf16_t* __restrict__ Vf, bf16_t* __restrict__ Pacc,
    float* __restrict__ Pml)
{
    __shared__ __attribute__((aligned(16))) bf16_t Pl[4][32][40];
    const int tid = threadIdx.x, lane = tid & 63, wid = tid >> 6;
    const int g = lane >> 4, c = lane & 15;
    bf16_t (*P)[40] = Pl[wid];

    const int bx = blockIdx.x;
    const int b  = bx & 7;                       // XCD-pinned batch
    const int u  = 287 - ((bx >> 3) * 4 + wid);  // long-units-first
    int k = 0;
    while (4 * (k + 1) * (k + 2) <= u) ++k;      // tier k = qt>>3, 0..7
    const int r  = u - 4 * k * (k + 1);
    const int qt = 8 * k + r / (k + 1);
    const int ch = r - (r / (k + 1)) * (k + 1);
    const int q0 = qt * 32;
    const int kv_lo = ch * 256;
    int kv_hi = kv_lo + 256; if (kv_hi > q0 + 32) kv_hi = q0 + 32;
    const int sid = b * UPB + 4 * k * (k + 1) + (qt & 7) * (k + 1) + ch;

    bf16x8 qA[4], qB[4];
    for (int kk = 0; kk < 4; ++kk) {
        qA[kk] = *(const bf16x8*)(Qf +
            ((size_t)((b * 128 + (q0 >> 4)) * 4 + kk)) * 512 + lane * 8);
        qB[kk] = *(const bf16x8*)(Qf +
            ((size_t)((b * 128 + (q0 >> 4) + 1) * 4 + kk)) * 512 + lane * 8);
    }

    f32x4 accA[8], accB[8];
    for (int hb = 0; hb < 8; ++hb) { accA[hb] = (f32x4)0.0f; accB[hb] = (f32x4)0.0f; }
    float lsA[4] = {0, 0, 0, 0}, lsB[4] = {0, 0, 0, 0};

    for (int kv0 = kv_lo; kv0 < kv_hi; kv0 += 32) {
        const int kt = b * 128 + (kv0 >> 4);
        bf16x8 k0f[4], k1f[4], vf[8];
        for (int kk = 0; kk < 4; ++kk) {
            k0f[kk] = *(const bf16x8*)(Kf + ((size_t)(kt * 4 + kk)) * 512 + lane * 8);
            k1f[kk] = *(const bf16x8*)(Kf + ((size_t)((kt + 1) * 4 + kk)) * 512 + lane * 8);
        }
        const int vcb = (b * 64 + (kv0 >> 5)) * 8;
        for (int hb = 0; hb < 8; ++hb)
            vf[hb] = *(const bf16x8*)(Vf + ((size_t)(vcb + hb)) * 512 + lane * 8);

        f32x4 sA0 = (f32x4)0.0f, sA1 = (f32x4)0.0f;
        f32x4 sB0 = (f32x4)0.0f, sB1 = (f32x4)0.0f;
        for (int kk = 0; kk < 4; ++kk) {
            sA0 = MFMA16(qA[kk], k0f[kk], sA0);
            sA1 = MFMA16(qA[kk], k1f[kk], sA1);
            sB0 = MFMA16(qB[kk], k0f[kk], sB0);
            sB1 = MFMA16(qB[kk], k1f[kk], sB1);
        }
        if (kv0 + 32 > q0) {                     // causal mask, subtile A
            for (int i = 0; i < 4; ++i) {
                int row = q0 + g * 4 + i;
                if (kv0 + c > row)      sA0[i] = -1e30f;
                if (kv0 + 16 + c > row) sA1[i] = -1e30f;
            }
        }
        if (kv0 + 32 > q0 + 16) {                // causal mask, subtile B
            for (int i = 0; i < 4; ++i) {
                int row = q0 + 16 + g * 4 + i;
                if (kv0 + c > row)      sB0[i] = -1e30f;
                if (kv0 + 16 + c > row) sB1[i] = -1e30f;
            }
        }
        float pA0[4], pA1[4], pB0[4], pB1[4];
        for (int i = 0; i < 4; ++i) {            // p = 2^s (log2e folded into Q)
            pA0[i] = exp2f(sA0[i]); pA1[i] = exp2f(sA1[i]);
            pB0[i] = exp2f(sB0[i]); pB1[i] = exp2f(sB1[i]);
            lsA[i] += pA0[i] + pA1[i];
            lsB[i] += pB0[i] + pB1[i];
        }
        for (int i = 0; i < 4; ++i) {
            P[g * 4 + i][c]           = (bf16_t)pA0[i];
            P[g * 4 + i][c + 16]      = (bf16_t)pA1[i];
            P[16 + g * 4 + i][c]      = (bf16_t)pB0[i];
            P[16 + g * 4 + i][c + 16] = (bf16_t)pB1[i];
        }
        __builtin_amdgcn_wave_barrier();
        asm volatile("s_waitcnt lgkmcnt(0)" ::: "memory");
        __builtin_amdgcn_sched_barrier(0);
        bf16x8 paA = *(const bf16x8*)&P[c][g * 8];
        bf16x8 paB = *(const bf16x8*)&P[16 + c][g * 8];
        __builtin_amdgcn_s_setprio(1);
        for (int hb = 0; hb < 8; ++hb) {
            accA[hb] = MFMA16(paA, vf[hb], accA[hb]);
            accB[hb] = MFMA16(paB, vf[hb], accB[hb]);
        }
        __builtin_amdgcn_s_setprio(0);
        __builtin_amdgcn_wave_barrier();
    }

    for (int off = 1; off < 16; off <<= 1)
        for (int i = 0; i < 4; ++i) {
            lsA[i] += __shfl_xor(lsA[i], off, 64);
            lsB[i] += __shfl_xor(lsB[i], off, 64);
        }
    if (c == 0)
        for (int i = 0; i < 4; ++i) {
            Pml[(size_t)sid * 32 + g * 4 + i]      = lsA[i];
            Pml[(size_t)sid * 32 + 16 + g * 4 + i] = lsB[i];
        }

    // Pacc transposed: po[col=128][row=32]; packed 8B stores
    bf16_t* po = Pacc + (size_t)sid * (32 * 128);
    for (int hb = 0; hb < 8; ++hb) {
        union { bf16_t h4[4]; unsigned long long u; } pa, pb;
        for (int i = 0; i < 4; ++i) {
            pa.h4[i] = (bf16_t)accA[hb][i];
            pb.h4[i] = (bf16_t)accB[hb][i];
        }
        bf16_t* cp = po + (hb * 16 + c) * 32;
        *reinterpret_cast<unsigned long long*>(cp + g * 4)      = pa.u;
        *reinterpret_cast<unsigned long long*>(cp + 16 + g * 4) = pb.u;
    }
}

// ---------------- combine partials (plain sums; Pacc is [col][row]) ----------------
__global__ __launch_bounds__(128) void combine_kernel(
    const bf16_t* __restrict__ Pacc, const float* __restrict__ Pml,
    float* __restrict__ out)
{
    __shared__ float invL[32];
    const int qt = blockIdx.x;                   // 0..63
    const int b  = blockIdx.y;
    const int k  = qt >> 3;
    const int base  = b * UPB + 4 * k * (k + 1) + (qt & 7) * (k + 1);
    const int count = k + 1;
    const int tid = threadIdx.x;                 // = col 0..127

    if (tid < 32) {
        float L = 0.0f;
        for (int cu = 0; cu < count; ++cu)
            L += Pml[(size_t)(base + cu) * 32 + tid];
        invL[tid] = 1.0f / L;
    }
    __syncthreads();

    float s[32];
    for (int r = 0; r < 32; ++r) s[r] = 0.0f;
    for (int cu = 0; cu < count; ++cu) {
        const bf16_t* cp = Pacc + (size_t)(base + cu) * 4096 + tid * 32;
        for (int r8 = 0; r8 < 4; ++r8) {
            bf16x8 v = *(const bf16x8*)(cp + r8 * 8);
            for (int j = 0; j < 8; ++j) s[r8 * 8 + j] += (float)v[j];
        }
    }
    const int q0 = qt * 32;
    for (int r = 0; r < 32; ++r)
        out[((size_t)b * TT + q0 + r) * HH + tid] = s[r] * invL[r];
}

extern "C" void kernel_launch(void* const* d_in, const int* in_sizes, int n_in,
                              void* d_out, int out_size, void* d_ws, size_t ws_size,
                              hipStream_t stream)
{
    const float* x  = (const float*)d_in[0];
    const float* Wq = (const float*)d_in[1];
    const float* Wk = (const float*)d_in[2];
    const float* Wv = (const float*)d_in[3];

    char* ws = (char*)d_ws;
    bf16_t* Wf   = (bf16_t*)ws;                       // 768 KB fragment-major
    bf16_t* Qf   = (bf16_t*)(ws + (1u  << 20));       // 4 MB fragment-major
    bf16_t* Kf   = (bf16_t*)(ws + (5u  << 20));       // 4 MB fragment-major
    bf16_t* Vf   = (bf16_t*)(ws + (9u  << 20));       // 4 MB fragment-major
    bf16_t* Pacc = (bf16_t*)(ws + (13u << 20));       // 2304*8192 B = 18.9 MB
    float*  Pml  = (float*) (ws + (32u << 20));       // 2304*128 B

    prep_w_kernel<<<1536, 256, 0, stream>>>(Wq, Wk, Wv, Wf);
    qkv_kernel<<<512, 256, 0, stream>>>(x, Wf, Qf, Kf, Vf);
    attn_kernel<<<576, 256, 0, stream>>>(Qf, Kf, Vf, Pacc, Pml);
    combine_kernel<<<dim3(64, 8), 128, 0, stream>>>(Pacc, Pml, (float*)d_out);
}